// Round 9
// baseline (99.267 us; speedup 1.0000x reference)
//
#include <hip/hip_runtime.h>

// SGAN_PoolingNet: pooled[i] = max_j relu( relu([hidden[j], (ends[j]-ends[i])@We+be] @ W1 + b1) @ W2 + b2 )
// Collapse: y_lin[i,j,:] = A[j,:] - U[i,:]
//   A[j,k] = hidden[j]@W1[0:64,k] + ends[j]@M2[:,k] + b1[k] + be@W1[64:80,k]   (f32 math, stored f16)
//   U[i,k] = ends[i]@M2[:,k],  M2 = We @ W1[64:80,:]  (2x128, f32)
// R12: depth-3 was NULL (94.5 vs 92.2) -> pool (~29us vs ~3us issue floor) is NOT
//     prefetch-distance-limited; it's contention/latency on 512 blocks x 256KB = 128MB of
//     scattered per-lane A reads. Restructure:
//  (a) G=4 agents/block, 512 thr, grid 256 (1 block/CU, single resident round): traffic 64MB,
//      each A tile loaded once per block, consumed by 4 waves (wave = agent x tile-parity).
//  (b) LDS-staged A (8KB/round, dbuf, T14 split: global->reg at round start, ds_write after
//      compute): block-coalesced streaming instead of per-lane scatter; latency hides under
//      ~500cy compute; one barrier/round.
//  (c) [64-col-row x f16] LDS tile is a 16-way bank conflict (G4) -> XOR-swizzle
//      byte ^= (row&7)<<4 on ds_read; prep PRE-SWIZZLES A's 16B col-groups globally
//      (col' = ((k>>3)^(j&7))*8 + (k&7)) so linear stage + swizzled read compose (rule #21;
//      (tile*16+m)&7 == m&7 so the XOR is tile-independent).
//  Regs: ~70 VGPR + 64 AGPR(bfrag) = ~134 unified < 256 cap @ launch_bounds(512,2) -> no spill.

#define N_AG 1024
#define JT 4

typedef __attribute__((ext_vector_type(8))) _Float16 half8;      // 8 f16 = 4 VGPR (MFMA A/B frag)
typedef __attribute__((ext_vector_type(4))) float floatx4;       // MFMA C/D frag
typedef __attribute__((ext_vector_type(4))) unsigned int uintx4; // 4 packed f16 pairs

__device__ __forceinline__ unsigned short f2h(float f) {
  return __builtin_bit_cast(unsigned short, (_Float16)f);   // RNE
}

// d = max(a - u, 0) elementwise on packed f16 pairs: 2 VALU instrs, no unpack.
__device__ __forceinline__ unsigned pk_sub_relu(unsigned a, unsigned u) {
  unsigned d;
  asm("v_pk_add_f16 %0, %1, %2 neg_lo:[0,1] neg_hi:[0,1]\n\t"
      "v_pk_max_f16 %0, %0, 0"
      : "=v"(d) : "v"(a), "v"(u));
  return d;
}

// ---- prep: block jb computes A[4jb..4jb+3] (column-group-swizzled); block 0 writes M2;
// ---- blocks 0..31 write W2T ----
__global__ __launch_bounds__(128) void prep_all(
    const float* __restrict__ hidden,  // (1,1024,64)
    const float* __restrict__ track,   // (1024,8,2)
    const float* __restrict__ We,      // (2,16)
    const float* __restrict__ be,      // (16)
    const float* __restrict__ W1,      // (80,128)
    const float* __restrict__ b1,      // (128)
    const float* __restrict__ W2,      // (128,64)
    unsigned short* __restrict__ Ah,   // (1024,128) f16, col-groups swizzled per row
    float* __restrict__ M2f,           // (2,128) f32
    unsigned short* __restrict__ W2T)  // (64,128) f16
{
  const int jb = blockIdx.x;          // 0..255
  const int j0 = jb * JT;
  const int k  = threadIdx.x;         // 0..127
  __shared__ float hs[JT][64];
#pragma unroll
  for (int q = k; q < JT * 64; q += 128) hs[q >> 6][q & 63] = hidden[j0 * 64 + q];
  __syncthreads();

  float m20 = 0.f, m21 = 0.f, cb = b1[k];
#pragma unroll
  for (int t = 0; t < 16; ++t) {
    float w1v = W1[(64 + t) * 128 + k];
    m20 += We[t] * w1v;
    m21 += We[16 + t] * w1v;
    cb  += be[t] * w1v;
  }
  float acc[JT];
#pragma unroll
  for (int jj = 0; jj < JT; ++jj) {
    float e0 = track[(j0 + jj) * 16 + 14];
    float e1 = track[(j0 + jj) * 16 + 15];
    acc[jj] = e0 * m20 + e1 * m21 + cb;
  }
#pragma unroll 8
  for (int t = 0; t < 64; ++t) {
    float w = W1[t * 128 + k];
#pragma unroll
    for (int jj = 0; jj < JT; ++jj) acc[jj] += hs[jj][t] * w;
  }
  // swizzled store: 16B col-group g -> slot g ^ (j&7); within-group offset preserved.
#pragma unroll
  for (int jj = 0; jj < JT; ++jj) {
    int j = j0 + jj;
    int colp = (((k >> 3) ^ (j & 7)) << 3) | (k & 7);
    __builtin_nontemporal_store(f2h(acc[jj]), &Ah[j * 128 + colp]);
  }

  if (jb == 0) {          // m20/m21 are exactly M2[0][k], M2[1][k]
    M2f[k]       = m20;
    M2f[128 + k] = m21;
  }
  if (jb < 32) {          // W2T[n][c] = f16(W2[c][n]); 32 blocks x 256 entries
#pragma unroll
    for (int q = 0; q < 2; ++q) {
      int idx = jb * 256 + q * 128 + k;
      int n = idx >> 7, c = idx & 127;
      W2T[n * 128 + c] = f2h(W2[c * 64 + n]);
    }
  }
}

// ---- main: one block per 4 agents; 8 waves = 4(agent) x 2(tile parity); A via LDS dbuf ----
__global__ __launch_bounds__(512, 2) void pool_main(
    const unsigned short* __restrict__ Ah,    // (1024,128) f16, swizzled
    const float* __restrict__ M2f,            // (2,128) f32
    const float* __restrict__ track,          // (1024,8,2) f32
    const unsigned short* __restrict__ W2T,   // (64,128) f16
    const float* __restrict__ b2,             // (64) f32
    float* __restrict__ out)                  // (1024,64) f32
{
  const int tid  = threadIdx.x;
  const int lane = tid & 63;
  const int w    = tid >> 6;   // wave 0..7
  const int g    = w >> 1;     // agent slot 0..3
  const int par  = w & 1;      // tile parity: this wave does tiles t = 2r + par
  const int m    = lane & 15;  // A row within tile / output col within nt-block
  const int quad = lane >> 4;  // k-subrange selector
  const int i    = blockIdx.x * 4 + g;

  __shared__ __align__(16) unsigned short Abuf[2][2][16][128]; // [dbuf][par][row][col] 16KB
  __shared__ float red[8][64];

  const char* Asrc = (const char*)Ah;

  // prologue: stage rows 0..31 (tiles 0,1) into Abuf[0]
  {
    uintx4 v = *(const uintx4*)(Asrc + tid * 16);
    *(uintx4*)((char*)Abuf[0] + tid * 16) = v;
  }

  // U[i] as packed f16 pairs matching A's dword element order (pre-swizzle order)
  const float e0 = track[i * 16 + 14];
  const float e1 = track[i * 16 + 15];
  unsigned upk[4][4];
#pragma unroll
  for (int kk = 0; kk < 4; ++kk) {
#pragma unroll
    for (int p = 0; p < 4; ++p) {
      int k0 = kk * 32 + quad * 8 + 2 * p;
      float a = e0 * M2f[k0]     + e1 * M2f[128 + k0];
      float b = e0 * M2f[k0 + 1] + e1 * M2f[128 + k0 + 1];
      upk[kk][p] = (unsigned)f2h(a) | ((unsigned)f2h(b) << 16);
    }
  }

  // full 64-col B panel (4 x 16-col blocks), register/AGPR-resident
  half8 bfrag[4][4];
#pragma unroll
  for (int nt = 0; nt < 4; ++nt)
#pragma unroll
    for (int kk = 0; kk < 4; ++kk)
      bfrag[nt][kk] = *(const half8*)(W2T + (nt * 16 + m) * 128 + kk * 32 + quad * 8);

  floatx4 mx[4];
#pragma unroll
  for (int nt = 0; nt < 4; ++nt) mx[nt] = (floatx4){-3e38f, -3e38f, -3e38f, -3e38f};

  __syncthreads();

#pragma unroll 1
  for (int r = 0; r < 32; ++r) {
    // T14 split: issue next round's global load first (latency hides under compute)
    uintx4 stg;
    const bool more = (r + 1) < 32;
    if (more) stg = *(const uintx4*)(Asrc + (r + 1) * 8192 + tid * 16);

    // compute this wave's tile (t = 2r+par) for agent i
    const char* T = (const char*)Abuf[r & 1][par];
    uintx4 au[4];
#pragma unroll
    for (int kk = 0; kk < 4; ++kk) {
      // swizzled read: slot = (kk*4+quad) ^ (m&7); undoes prep's pre-swizzle (j&7 == m&7)
      unsigned byteoff = (unsigned)(m * 256 + (((kk * 4 + quad) ^ (m & 7)) << 4));
      uintx4 raw = *(const uintx4*)(T + byteoff);
#pragma unroll
      for (int p = 0; p < 4; ++p) au[kk][p] = pk_sub_relu(raw[p], upk[kk][p]);
    }
#pragma unroll
    for (int nt = 0; nt < 4; ++nt) {
      floatx4 acc = (floatx4){0.f, 0.f, 0.f, 0.f};
#pragma unroll
      for (int kk = 0; kk < 4; ++kk)
        acc = __builtin_amdgcn_mfma_f32_16x16x32_f16(
            __builtin_bit_cast(half8, au[kk]), bfrag[nt][kk], acc, 0, 0, 0);
#pragma unroll
      for (int rr = 0; rr < 4; ++rr) mx[nt][rr] = fmaxf(mx[nt][rr], acc[rr]);
    }

    // write-late: park next tiles in the other LDS buffer, then one barrier
    if (more) *(uintx4*)((char*)Abuf[(r + 1) & 1] + tid * 16) = stg;
    __syncthreads();
  }

  // D layout: row = quad*4 + rr (j within tile), col = nt*16 + m. Reduce rows in-lane,
  // across quads via shfl, across the parity pair via LDS; agents are disjoint waves.
#pragma unroll
  for (int nt = 0; nt < 4; ++nt) {
    float a = fmaxf(fmaxf(mx[nt][0], mx[nt][1]), fmaxf(mx[nt][2], mx[nt][3]));
    a = fmaxf(a, __shfl_xor(a, 16, 64));
    a = fmaxf(a, __shfl_xor(a, 32, 64));
    if (quad == 0) red[w][nt * 16 + m] = a;
  }
  __syncthreads();
  if (tid < 256) {
    int gg = tid >> 6, n = tid & 63;
    float v = fmaxf(red[2 * gg][n], red[2 * gg + 1][n]);
    v += b2[n];
    out[(blockIdx.x * 4 + gg) * 64 + n] = v > 0.f ? v : 0.f;
  }
}

extern "C" void kernel_launch(void* const* d_in, const int* in_sizes, int n_in,
                              void* d_out, int out_size, void* d_ws, size_t ws_size,
                              hipStream_t stream) {
  const float* hidden = (const float*)d_in[0]; // (1,1024,64)
  const float* track  = (const float*)d_in[1]; // (1024,8,2)
  const float* We     = (const float*)d_in[2]; // (2,16)
  const float* be     = (const float*)d_in[3]; // (16)
  const float* W1     = (const float*)d_in[4]; // (80,128)
  const float* b1     = (const float*)d_in[5]; // (128)
  const float* W2     = (const float*)d_in[6]; // (128,64)
  const float* b2     = (const float*)d_in[7]; // (64)
  float* out = (float*)d_out;

  char* ws = (char*)d_ws;
  unsigned short* Ah  = (unsigned short*)ws;              // 1024*128*2 = 256 KiB
  float*          M2f = (float*)(ws + 262144);            // 256*4     = 1 KiB
  unsigned short* W2T = (unsigned short*)(ws + 263168);   // 64*128*2  = 16 KiB

  prep_all<<<N_AG / JT, 128, 0, stream>>>(hidden, track, We, be, W1, b1, W2, Ah, M2f, W2T);
  pool_main<<<N_AG / 4, 512, 0, stream>>>(Ah, M2f, track, W2T, b2, out);
}

// Round 10
// 93.024 us; speedup vs baseline: 1.0671x; 1.0671x over previous
//
#include <hip/hip_runtime.h>

// SGAN_PoolingNet: pooled[i] = max_j relu( relu([hidden[j], (ends[j]-ends[i])@We+be] @ W1 + b1) @ W2 + b2 )
// Collapse: y_lin[i,j,:] = A[j,:] - U[i,:]
//   A[j,k] = hidden[j]@W1[0:64,k] + ends[j]@M2[:,k] + b1[k] + be@W1[64:80,k]   (f32 math, stored f16)
//   U[i,k] = ends[i]@M2[:,k],  M2 = We @ W1[64:80,:]  (2x128, f32)
// R13: R12 (G=4 + LDS dbuf + 32 barriers) REGRESSED (99.3 vs R5's 92.2). With R8 (depth-3 null)
//     that's 3 structural nulls: pool is neither prefetch-depth- nor BW-limited, and per-round
//     barriers EXPOSE latency that R5's free-running waves absorb. Revert to proven-best skeleton
//     (R5: G=2, depth-2 register ring, zero in-loop barriers, unswizzled NT prep stores) + two
//     cheap orthogonal deltas:
//  (a) prep JT 4->2, grid 512 (2 blocks/CU): prep is latency-bound W1 streaming with ~no TLP;
//      2x resident waves ~halves its ~5us.
//  (b) T5 s_setprio(1) around MFMA clusters: waves here are free-running/phase-staggered
//      (attn-like, +4-7% there), not barrier-lockstep (null there). Zero cost if null.

#define N_AG 1024
#define JT 2

typedef __attribute__((ext_vector_type(8))) _Float16 half8;      // 8 f16 = 4 VGPR (MFMA A/B frag)
typedef __attribute__((ext_vector_type(4))) float floatx4;       // MFMA C/D frag
typedef __attribute__((ext_vector_type(4))) unsigned int uintx4; // 4 packed f16 pairs

__device__ __forceinline__ unsigned short f2h(float f) {
  return __builtin_bit_cast(unsigned short, (_Float16)f);   // RNE
}

// d = max(a - u, 0) elementwise on packed f16 pairs: 2 VALU instrs, no unpack.
__device__ __forceinline__ unsigned pk_sub_relu(unsigned a, unsigned u) {
  unsigned d;
  asm("v_pk_add_f16 %0, %1, %2 neg_lo:[0,1] neg_hi:[0,1]\n\t"
      "v_pk_max_f16 %0, %0, 0"
      : "=v"(d) : "v"(a), "v"(u));
  return d;
}

// ---- prep: block jb computes A[2jb..2jb+1]; block 0 writes M2; blocks 0..31 write W2T ----
__global__ __launch_bounds__(128) void prep_all(
    const float* __restrict__ hidden,  // (1,1024,64)
    const float* __restrict__ track,   // (1024,8,2)
    const float* __restrict__ We,      // (2,16)
    const float* __restrict__ be,      // (16)
    const float* __restrict__ W1,      // (80,128)
    const float* __restrict__ b1,      // (128)
    const float* __restrict__ W2,      // (128,64)
    unsigned short* __restrict__ Ah,   // (1024,128) f16
    float* __restrict__ M2f,           // (2,128) f32
    unsigned short* __restrict__ W2T)  // (64,128) f16
{
  const int jb = blockIdx.x;          // 0..511
  const int j0 = jb * JT;
  const int k  = threadIdx.x;         // 0..127
  __shared__ float hs[JT][64];
  hs[k >> 6][k & 63] = hidden[j0 * 64 + k];   // 128 threads load JT*64=128 floats
  __syncthreads();

  float m20 = 0.f, m21 = 0.f, cb = b1[k];
#pragma unroll
  for (int t = 0; t < 16; ++t) {
    float w1v = W1[(64 + t) * 128 + k];
    m20 += We[t] * w1v;
    m21 += We[16 + t] * w1v;
    cb  += be[t] * w1v;
  }
  float acc[JT];
#pragma unroll
  for (int jj = 0; jj < JT; ++jj) {
    float e0 = track[(j0 + jj) * 16 + 14];
    float e1 = track[(j0 + jj) * 16 + 15];
    acc[jj] = e0 * m20 + e1 * m21 + cb;
  }
#pragma unroll 8
  for (int t = 0; t < 64; ++t) {
    float w = W1[t * 128 + k];
#pragma unroll
    for (int jj = 0; jj < JT; ++jj) acc[jj] += hs[jj][t] * w;
  }
#pragma unroll
  for (int jj = 0; jj < JT; ++jj)
    __builtin_nontemporal_store(f2h(acc[jj]), &Ah[(j0 + jj) * 128 + k]);

  if (jb == 0) {          // m20/m21 are exactly M2[0][k], M2[1][k]
    M2f[k]       = m20;
    M2f[128 + k] = m21;
  }
  if (jb < 32) {          // W2T[n][c] = f16(W2[c][n]); 32 blocks x 256 entries
#pragma unroll
    for (int q = 0; q < 2; ++q) {
      int idx = jb * 256 + q * 128 + k;
      int n = idx >> 7, c = idx & 127;
      W2T[n * 128 + c] = f2h(W2[c * 64 + n]);
    }
  }
}

// ---- main: one block per 2 agents; 4 waves split j 4-way (disjoint), each full 64 cols ----
__global__ __launch_bounds__(256, 2) void pool_main(
    const unsigned short* __restrict__ Ah,    // (1024,128) f16
    const float* __restrict__ M2f,            // (2,128) f32
    const float* __restrict__ track,          // (1024,8,2) f32
    const unsigned short* __restrict__ W2T,   // (64,128) f16
    const float* __restrict__ b2,             // (64) f32
    float* __restrict__ out)                  // (1024,64) f32
{
  const int i0   = blockIdx.x * 2;
  const int lane = threadIdx.x & 63;
  const int w    = threadIdx.x >> 6;   // wave 0..3: j-tiles jt = 4t + w
  const int m    = lane & 15;          // A row within tile / B-and-D column
  const int quad = lane >> 4;          // k-subrange selector

  const int TSTEP = 4 * 16 * 128;      // elems between this wave's consecutive tiles
  const unsigned short* base = Ah + (w * 16 + m) * 128 + quad * 8;

  // depth-2 register ring: issue tiles 0,1 of this wave ASAP
  uintx4 buf0[4], buf1[4];
#pragma unroll
  for (int kk = 0; kk < 4; ++kk) buf0[kk] = *(const uintx4*)(base + kk * 32);
#pragma unroll
  for (int kk = 0; kk < 4; ++kk) buf1[kk] = *(const uintx4*)(base + TSTEP + kk * 32);

  // U[i0], U[i0+1] as packed f16 pairs matching A's dword element order
  const float a0 = track[i0 * 16 + 14];
  const float a1 = track[i0 * 16 + 15];
  const float c0 = track[(i0 + 1) * 16 + 14];
  const float c1 = track[(i0 + 1) * 16 + 15];
  unsigned upkA[4][4], upkB[4][4];
#pragma unroll
  for (int kk = 0; kk < 4; ++kk) {
#pragma unroll
    for (int p = 0; p < 4; ++p) {
      int k0 = kk * 32 + quad * 8 + 2 * p;
      float m0 = M2f[k0],     m0h = M2f[128 + k0];
      float m1 = M2f[k0 + 1], m1h = M2f[128 + k0 + 1];
      upkA[kk][p] = (unsigned)f2h(a0 * m0 + a1 * m0h) | ((unsigned)f2h(a0 * m1 + a1 * m1h) << 16);
      upkB[kk][p] = (unsigned)f2h(c0 * m0 + c1 * m0h) | ((unsigned)f2h(c0 * m1 + c1 * m1h) << 16);
    }
  }

  // full 64-col B panel per wave (4 x 16-col blocks), register/AGPR-resident
  half8 bfrag[4][4];
#pragma unroll
  for (int nt = 0; nt < 4; ++nt)
#pragma unroll
    for (int kk = 0; kk < 4; ++kk)
      bfrag[nt][kk] = *(const half8*)(W2T + (nt * 16 + m) * 128 + kk * 32 + quad * 8);

  floatx4 mxA[4], mxB[4];
#pragma unroll
  for (int nt = 0; nt < 4; ++nt) {
    mxA[nt] = (floatx4){-3e38f, -3e38f, -3e38f, -3e38f};
    mxB[nt] = (floatx4){-3e38f, -3e38f, -3e38f, -3e38f};
  }

  const unsigned short* pn = base + 2 * TSTEP;   // next tile to load (t+2)

  // body: repack+MFMA both agents for tile in BUF; optionally prefetch tile at pn.
  auto body = [&](uintx4 (&BUF)[4], bool do_load) {
    uintx4 au[4];
#pragma unroll
    for (int kk = 0; kk < 4; ++kk)
#pragma unroll
      for (int p = 0; p < 4; ++p) au[kk][p] = pk_sub_relu(BUF[kk][p], upkA[kk][p]);
    __builtin_amdgcn_s_setprio(1);
#pragma unroll
    for (int nt = 0; nt < 4; ++nt) {
      floatx4 acc = (floatx4){0.f, 0.f, 0.f, 0.f};
#pragma unroll
      for (int kk = 0; kk < 4; ++kk)
        acc = __builtin_amdgcn_mfma_f32_16x16x32_f16(
            __builtin_bit_cast(half8, au[kk]), bfrag[nt][kk], acc, 0, 0, 0);
#pragma unroll
      for (int r = 0; r < 4; ++r) mxA[nt][r] = fmaxf(mxA[nt][r], acc[r]);
    }
    __builtin_amdgcn_s_setprio(0);
#pragma unroll
    for (int kk = 0; kk < 4; ++kk)
#pragma unroll
      for (int p = 0; p < 4; ++p) au[kk][p] = pk_sub_relu(BUF[kk][p], upkB[kk][p]);
    if (do_load) {
#pragma unroll
      for (int kk = 0; kk < 4; ++kk) BUF[kk] = *(const uintx4*)(pn + kk * 32);
      pn += TSTEP;
    }
    __builtin_amdgcn_s_setprio(1);
#pragma unroll
    for (int nt = 0; nt < 4; ++nt) {
      floatx4 acc = (floatx4){0.f, 0.f, 0.f, 0.f};
#pragma unroll
      for (int kk = 0; kk < 4; ++kk)
        acc = __builtin_amdgcn_mfma_f32_16x16x32_f16(
            __builtin_bit_cast(half8, au[kk]), bfrag[nt][kk], acc, 0, 0, 0);
#pragma unroll
      for (int r = 0; r < 4; ++r) mxB[nt][r] = fmaxf(mxB[nt][r], acc[r]);
    }
    __builtin_amdgcn_s_setprio(0);
  };

  // 16 tiles/wave, depth-2 ring: bodies t=0..13 load t+2 (tiles 2..15); t=14,15 drain.
#pragma unroll 1
  for (int t2 = 0; t2 < 14; t2 += 2) {
    body(buf0, true);
    body(buf1, true);
  }
  body(buf0, false);   // t=14
  body(buf1, false);   // t=15

  // D layout: row = quad*4 + r (j within tile), col = nt*16 + m. Reduce rows in-lane,
  // across quads via shfl, across the 4 j-waves via LDS. Two agents' results side by side.
  __shared__ float red[2][4][64];
#pragma unroll
  for (int nt = 0; nt < 4; ++nt) {
    float a = fmaxf(fmaxf(mxA[nt][0], mxA[nt][1]), fmaxf(mxA[nt][2], mxA[nt][3]));
    a = fmaxf(a, __shfl_xor(a, 16, 64));
    a = fmaxf(a, __shfl_xor(a, 32, 64));
    float b = fmaxf(fmaxf(mxB[nt][0], mxB[nt][1]), fmaxf(mxB[nt][2], mxB[nt][3]));
    b = fmaxf(b, __shfl_xor(b, 16, 64));
    b = fmaxf(b, __shfl_xor(b, 32, 64));
    if (quad == 0) {
      red[0][w][nt * 16 + m] = a;
      red[1][w][nt * 16 + m] = b;
    }
  }
  __syncthreads();
  if (threadIdx.x < 128) {
    int g = threadIdx.x >> 6, n = threadIdx.x & 63;
    float v = fmaxf(fmaxf(red[g][0][n], red[g][1][n]), fmaxf(red[g][2][n], red[g][3][n]));
    v += b2[n];
    out[(i0 + g) * 64 + n] = v > 0.f ? v : 0.f;
  }
}

extern "C" void kernel_launch(void* const* d_in, const int* in_sizes, int n_in,
                              void* d_out, int out_size, void* d_ws, size_t ws_size,
                              hipStream_t stream) {
  const float* hidden = (const float*)d_in[0]; // (1,1024,64)
  const float* track  = (const float*)d_in[1]; // (1024,8,2)
  const float* We     = (const float*)d_in[2]; // (2,16)
  const float* be     = (const float*)d_in[3]; // (16)
  const float* W1     = (const float*)d_in[4]; // (80,128)
  const float* b1     = (const float*)d_in[5]; // (128)
  const float* W2     = (const float*)d_in[6]; // (128,64)
  const float* b2     = (const float*)d_in[7]; // (64)
  float* out = (float*)d_out;

  char* ws = (char*)d_ws;
  unsigned short* Ah  = (unsigned short*)ws;              // 1024*128*2 = 256 KiB
  float*          M2f = (float*)(ws + 262144);            // 256*4     = 1 KiB
  unsigned short* W2T = (unsigned short*)(ws + 263168);   // 64*128*2  = 16 KiB

  prep_all<<<N_AG / JT, 128, 0, stream>>>(hidden, track, We, be, W1, b1, W2, Ah, M2f, W2T);
  pool_main<<<N_AG / 2, 256, 0, stream>>>(Ah, M2f, track, W2T, b2, out);
}